// Round 9
// baseline (261.904 us; speedup 1.0000x reference)
//
#include <hip/hip_runtime.h>

#define B_SZ 2
#define T_SZ 4096

typedef unsigned short u16;
typedef __attribute__((ext_vector_type(8))) short short8;
typedef __attribute__((ext_vector_type(4))) float f32x4;
typedef __attribute__((ext_vector_type(4))) unsigned short u16x4;

#define CEXP 0.51006973f   // (8^-0.5) * log2(e), folded into Q projection

__device__ __forceinline__ u16 f2bf(float f) {            // round-to-nearest-even
    unsigned int u;
    __builtin_memcpy(&u, &f, 4);
    u = (u + 0x7fffu + ((u >> 16) & 1u)) >> 16;
    return (u16)u;
}
__device__ __forceinline__ unsigned int rbits(float f) {  // bits + half-up round offset
    unsigned int u;
    __builtin_memcpy(&u, &f, 4);
    return u + 0x8000u;
}
__device__ __forceinline__ f32x4 mfma16(short8 a, short8 b, f32x4 c) {
    return __builtin_amdgcn_mfma_f32_16x16x32_bf16(a, b, c, 0, 0, 0);
}

// ---------- f32 [K][N] -> bf16 [N][K] (convert + transpose, weights only) ----------
__global__ void k_cvt_t(const float* __restrict__ src, u16* __restrict__ dst, int K, int N) {
    int idx = blockIdx.x * 256 + threadIdx.x;
    int k = idx / N, n = idx - k * N;
    dst[(size_t)n * K + k] = f2bf(src[idx]);
}

// ---------- LDS-tiled GEMM: C[M,N] = A[M,512] x Bt[N,512]^T ----------
// TM x TN tile, 4 waves (TM/2 x TN/2 quadrant each), BK=32, K=512.
// LDS rows 72 u16 (36 dw): reads/writes <=2-way bank aliasing (free).
// f32->bf16 convert fused into staging when AF32/BF32.
// MODE 0: C[row*N+col] (+bias). MODE 1 (qk): col<512 -> Qh[b,h,t,64]*CEXP; else Kh.
// MODE 2 (v): row=ch, col=tok -> Vb[b,h,kt,64d,64k] blocked.
template <typename OutT, int MODE, bool AF32, bool BF32, int TM, int TN>
__global__ __launch_bounds__(256) void k_gemm2(const void* __restrict__ Ap, const void* __restrict__ Bp,
                                               const float* __restrict__ bias, OutT* __restrict__ C,
                                               OutT* __restrict__ C2, int M, int N) {
    const int K = 512;
    constexpr int MI = TM / 32, NJ = TN / 32;            // 16x16 tiles per wave quadrant
    constexpr int NAF = TM * 32 / 1024, NAB = TM * 32 / 2048;
    constexpr int NBF = TN * 32 / 1024, NBB = TN * 32 / 2048;
    int m0 = blockIdx.x * TM, n0 = blockIdx.y * TN;
    int tid = threadIdx.x;
    int wave = tid >> 6, lane = tid & 63, l16 = lane & 15, q = lane >> 4;
    int mo = (wave & 1) * (TM / 2), no = (wave >> 1) * (TN / 2);

    __shared__ __align__(16) u16 As[TM * 72];
    __shared__ __align__(16) u16 Bs[TN * 72];

    f32x4 acc[MI][NJ];
#pragma unroll
    for (int i = 0; i < MI; ++i)
#pragma unroll
        for (int j = 0; j < NJ; ++j) acc[i][j] = (f32x4){0.f, 0.f, 0.f, 0.f};

    const float* Af = (const float*)Ap; const u16* Ab = (const u16*)Ap;
    const float* Bf = (const float*)Bp; const u16* Bb = (const u16*)Bp;

    // per-thread staging pointers (advanced by 32 along K each iter)
    const float* apf[NAF]; const u16* apb[NAB];
    const float* bpf[NBF]; const u16* bpb[NBB];
    float4 raf[NAF], rbf[NBF]; short8 rab[NAB], rbb[NBB];

    if constexpr (AF32) {
#pragma unroll
        for (int jj = 0; jj < NAF; ++jj) {
            int id = tid + 256 * jj;
            apf[jj] = Af + (size_t)(m0 + (id >> 3)) * K + (id & 7) * 4;
            raf[jj] = *(const float4*)(apf[jj]);
        }
    } else {
#pragma unroll
        for (int jj = 0; jj < NAB; ++jj) {
            int id = tid + 256 * jj;
            apb[jj] = Ab + (size_t)(m0 + (id >> 2)) * K + (id & 3) * 8;
            rab[jj] = *(const short8*)(apb[jj]);
        }
    }
    if constexpr (BF32) {
#pragma unroll
        for (int jj = 0; jj < NBF; ++jj) {
            int id = tid + 256 * jj;
            bpf[jj] = Bf + (size_t)(n0 + (id >> 3)) * K + (id & 7) * 4;
            rbf[jj] = *(const float4*)(bpf[jj]);
        }
    } else {
#pragma unroll
        for (int jj = 0; jj < NBB; ++jj) {
            int id = tid + 256 * jj;
            bpb[jj] = Bb + (size_t)(n0 + (id >> 2)) * K + (id & 3) * 8;
            rbb[jj] = *(const short8*)(bpb[jj]);
        }
    }

#pragma unroll 1
    for (int k0 = 0; k0 < K; k0 += 32) {
        __syncthreads();
        if constexpr (AF32) {
#pragma unroll
            for (int jj = 0; jj < NAF; ++jj) {
                int id = tid + 256 * jj;
                u16x4 w = { f2bf(raf[jj].x), f2bf(raf[jj].y), f2bf(raf[jj].z), f2bf(raf[jj].w) };
                *(u16x4*)(&As[(id >> 3) * 72 + (id & 7) * 4]) = w;
            }
        } else {
#pragma unroll
            for (int jj = 0; jj < NAB; ++jj) {
                int id = tid + 256 * jj;
                *(short8*)(&As[(id >> 2) * 72 + (id & 3) * 8]) = rab[jj];
            }
        }
        if constexpr (BF32) {
#pragma unroll
            for (int jj = 0; jj < NBF; ++jj) {
                int id = tid + 256 * jj;
                u16x4 w = { f2bf(rbf[jj].x), f2bf(rbf[jj].y), f2bf(rbf[jj].z), f2bf(rbf[jj].w) };
                *(u16x4*)(&Bs[(id >> 3) * 72 + (id & 7) * 4]) = w;
            }
        } else {
#pragma unroll
            for (int jj = 0; jj < NBB; ++jj) {
                int id = tid + 256 * jj;
                *(short8*)(&Bs[(id >> 2) * 72 + (id & 3) * 8]) = rbb[jj];
            }
        }
        __syncthreads();

        int kadv = (k0 + 32 < K) ? 32 : 0;
        if constexpr (AF32) {
#pragma unroll
            for (int jj = 0; jj < NAF; ++jj) { apf[jj] += kadv; raf[jj] = *(const float4*)(apf[jj]); }
        } else {
#pragma unroll
            for (int jj = 0; jj < NAB; ++jj) { apb[jj] += kadv; rab[jj] = *(const short8*)(apb[jj]); }
        }
        if constexpr (BF32) {
#pragma unroll
            for (int jj = 0; jj < NBF; ++jj) { bpf[jj] += kadv; rbf[jj] = *(const float4*)(bpf[jj]); }
        } else {
#pragma unroll
            for (int jj = 0; jj < NBB; ++jj) { bpb[jj] += kadv; rbb[jj] = *(const short8*)(bpb[jj]); }
        }
        __builtin_amdgcn_sched_barrier(0);

        short8 af[MI], bf[NJ];
#pragma unroll
        for (int i = 0; i < MI; ++i) af[i] = *(const short8*)(&As[(mo + i * 16 + l16) * 72 + q * 8]);
#pragma unroll
        for (int j = 0; j < NJ; ++j) bf[j] = *(const short8*)(&Bs[(no + j * 16 + l16) * 72 + q * 8]);
#pragma unroll
        for (int i = 0; i < MI; ++i)
#pragma unroll
            for (int j = 0; j < NJ; ++j) acc[i][j] = mfma16(af[i], bf[j], acc[i][j]);
    }

    // epilogue: D row = q*4+r (m), col = l16 (n)
#pragma unroll
    for (int i = 0; i < MI; ++i)
#pragma unroll
        for (int j = 0; j < NJ; ++j)
#pragma unroll
            for (int r = 0; r < 4; ++r) {
                int row = m0 + mo + i * 16 + q * 4 + r;
                int col = n0 + no + j * 16 + l16;
                float val = acc[i][j][r];
                if constexpr (MODE == 0) {
                    val += bias ? bias[col] : 0.f;
                    if constexpr (__is_same(OutT, float)) C[(size_t)row * N + col] = val;
                    else                                  C[(size_t)row * N + col] = f2bf(val);
                } else if constexpr (MODE == 1) {
                    int b = row >> 12, t = row & 4095, h = (col & 511) >> 6, d = col & 63;
                    size_t addr = ((size_t)((b * 8 + h) * 4096 + t)) * 64 + d;
                    if (col < 512) C[addr] = f2bf(val * CEXP);
                    else           C2[addr] = f2bf(val);
                } else { // MODE 2
                    int h = row >> 6, d = row & 63, b = col >> 12, t = col & 4095;
                    int kt = t >> 6, k64 = t & 63;
                    size_t addr = ((((size_t)(b * 8 + h) * 64 + kt) * 64 + d) << 6) + k64;
                    C[addr] = f2bf(val);
                }
            }
}

// ---------- flash attention: LDS-tiled + slot-reordered K + perm-packed P ----------
// grid (T/64, H, B); block 256 = 4 waves; wave owns 16 q rows. 64-key LDS tiles.
// Qh (pre-scaled)/Kh: [b,h,t,64]; Vb: [b,h,kt,64d,64k] blocked.
// K staged into LDS slot sigma(key) so A-frag reads are CONSECUTIVE slots l16:
//   slot s (sub-block of 32) holds key pi(s) = (s>>2&3... ) giving, with 88-u16
//   rows (44 dw), <=2-way bank aliasing on all Kt reads & writes (was 4-way).
//   MFMA result mapping unchanged: lane (l16,q) reg r = S[qrow=l16][key q*8+r(+4)].
// P packed via v_perm (1 op / 2 elems, round-half-up) -> PV B-frag directly.
// l via ones-A MFMA. No shuffles, no in-loop barough VALU beyond exp+pack.
__global__ __launch_bounds__(256) void k_flash(const u16* __restrict__ Qh, const u16* __restrict__ Kh,
                                               const u16* __restrict__ Vb, u16* __restrict__ o) {
    int qt = blockIdx.x, h = blockIdx.y, b = blockIdx.z;
    int tid = threadIdx.x;
    int wave = tid >> 6, lane = tid & 63, l16 = lane & 15, q = lane >> 4;

    __shared__ __align__(16) u16 Kt[64 * 88];   // [slot][d], 176B rows
    __shared__ __align__(16) u16 Vt[64 * 72];   // [d][key], 144B rows

    int head = b * 8 + h;
    const u16* qp = Qh + ((size_t)head * 4096 + qt * 64 + wave * 16 + l16) * 64 + q * 8;
    short8 qf0 = *(const short8*)(qp);
    short8 qf1 = *(const short8*)(qp + 32);

    const u16* kc = Kh + (size_t)head * 4096 * 64;   // tile kt: advance 4096 u16 (8KB)
    const u16* vc = Vb + (size_t)head * 4096 * 64;

    int r0 = tid >> 3, g0 = tid & 7;                 // key row 0..31, 16B granule
    int sig = ((r0 >> 2) & 1) * 16 + ((r0 >> 3) & 3) * 4 + (r0 & 3);  // key -> slot
    u16* kw0 = &Kt[sig * 88 + g0 * 8];
    u16* kw1 = &Kt[(sig + 32) * 88 + g0 * 8];        // key r0+32 -> slot sig+32
    u16* vw0 = &Vt[r0 * 72 + g0 * 8];
    u16* vw1 = &Vt[(r0 + 32) * 72 + g0 * 8];

    f32x4 oacc[4];
#pragma unroll
    for (int c = 0; c < 4; ++c) oacc[c] = (f32x4){0.f, 0.f, 0.f, 0.f};
    f32x4 lacc = (f32x4){0.f, 0.f, 0.f, 0.f};
    const short8 ones = { 0x3F80, 0x3F80, 0x3F80, 0x3F80, 0x3F80, 0x3F80, 0x3F80, 0x3F80 };

    short8 rk0 = *(const short8*)(kc + tid * 8);
    short8 rk1 = *(const short8*)(kc + tid * 8 + 2048);
    short8 rv0 = *(const short8*)(vc + tid * 8);
    short8 rv1 = *(const short8*)(vc + tid * 8 + 2048);

    const u16* kr = &Kt[l16 * 88 + q * 8];
    const u16* vr = &Vt[l16 * 72 + q * 8];

#pragma unroll 1
    for (int kt = 0; kt < 64; ++kt) {
        __syncthreads();
        *(short8*)kw0 = rk0;
        *(short8*)kw1 = rk1;
        *(short8*)vw0 = rv0;
        *(short8*)vw1 = rv1;
        __syncthreads();

        int adv = (kt < 63) ? 4096 : 0;              // last iter: harmless re-load
        kc += adv; vc += adv;
        rk0 = *(const short8*)(kc + tid * 8);
        rk1 = *(const short8*)(kc + tid * 8 + 2048);
        rv0 = *(const short8*)(vc + tid * 8);
        rv1 = *(const short8*)(vc + tid * 8 + 2048);
        __builtin_amdgcn_sched_barrier(0);

#pragma unroll
        for (int kk = 0; kk < 2; ++kk) {             // two 32-key subtiles
            const u16* ka = kr + kk * (32 * 88);
            short8 A00 = *(const short8*)(ka);
            short8 A01 = *(const short8*)(ka + 32);
            short8 A10 = *(const short8*)(ka + 16 * 88);
            short8 A11 = *(const short8*)(ka + 16 * 88 + 32);
            f32x4 s0 = (f32x4){0.f, 0.f, 0.f, 0.f};
            f32x4 s1 = (f32x4){0.f, 0.f, 0.f, 0.f};
            s0 = mfma16(A00, qf0, s0); s0 = mfma16(A01, qf1, s0);  // S^T keys q*8+r
            s1 = mfma16(A10, qf0, s1); s1 = mfma16(A11, qf1, s1);  // S^T keys q*8+4+r

            uint4 pd;
            pd.x = __builtin_amdgcn_perm(rbits(exp2f(s0[1])), rbits(exp2f(s0[0])), 0x07060302u);
            pd.y = __builtin_amdgcn_perm(rbits(exp2f(s0[3])), rbits(exp2f(s0[2])), 0x07060302u);
            pd.z = __builtin_amdgcn_perm(rbits(exp2f(s1[1])), rbits(exp2f(s1[0])), 0x07060302u);
            pd.w = __builtin_amdgcn_perm(rbits(exp2f(s1[3])), rbits(exp2f(s1[2])), 0x07060302u);
            short8 pf;
            __builtin_memcpy(&pf, &pd, 16);

            lacc = mfma16(ones, pf, lacc);           // l[qrow=l16] += slab sum
#pragma unroll
            for (int c = 0; c < 4; ++c) {
                short8 vfc = *(const short8*)(vr + c * (16 * 72) + kk * 32);
                oacc[c] = mfma16(vfc, pf, oacc[c]);  // O^T[d=c*16+q*4+r][qrow=l16]
            }
        }
    }

    float inv = 1.f / lacc[0];                       // every lane holds full l[qrow=l16]

    u16* ob = o + (size_t)(b * T_SZ + qt * 64 + wave * 16 + l16) * 512 + h * 64 + q * 4;
#pragma unroll
    for (int c = 0; c < 4; ++c) {
        u16x4 w = { f2bf(oacc[c][0] * inv), f2bf(oacc[c][1] * inv),
                    f2bf(oacc[c][2] * inv), f2bf(oacc[c][3] * inv) };
        *(u16x4*)(ob + c * 16) = w;
    }
}

extern "C" void kernel_launch(void* const* d_in, const int* in_sizes, int n_in,
                              void* d_out, int out_size, void* d_ws, size_t ws_size,
                              hipStream_t stream) {
    const float* x    = (const float*)d_in[0];   // [2,4096,512] f32
    const float* cond = (const float*)d_in[1];   // [2,4096,512] f32
    const float* Wqk  = (const float*)d_in[2];   // [512,1024]   f32
    const float* Wv   = (const float*)d_in[3];   // [512,512]    f32
    const float* Wu   = (const float*)d_in[4];   // [512,512]    f32
    const float* bu   = (const float*)d_in[5];   // [512]        f32
    float* out = (float*)d_out;                  // [2,4096,512] f32

    const size_t MT = (size_t)B_SZ * T_SZ;       // 8192
    u16* qh_ws = (u16*)d_ws;                     // [16 heads,4096,64]  8 MB (Q pre-scaled)
    u16* kh_ws = qh_ws + MT * 512;               // [16 heads,4096,64]  8 MB
    u16* vb_ws = kh_ws + MT * 512;               // [16,64kt,64d,64k]   8 MB
    u16* at_ws = vb_ws + MT * 512;               // [8192,512]          8 MB
    u16* Wqk_t = at_ws + MT * 512;               // [1024,512]          1 MB
    u16* Wv_t  = Wqk_t + (size_t)1024 * 512;     // [512,512]         0.5 MB
    u16* Wu_t  = Wv_t + (size_t)512 * 512;       // [512,512]         0.5 MB

    k_cvt_t<<<(512 * 1024) / 256, 256, 0, stream>>>(Wqk, Wqk_t, 512, 1024);
    k_cvt_t<<<(512 * 512) / 256, 256, 0, stream>>>(Wv, Wv_t, 512, 512);
    k_cvt_t<<<(512 * 512) / 256, 256, 0, stream>>>(Wu, Wu_t, 512, 512);

    // qk proj: A=cond (f32, convert-on-stage), B=Wqk_t -> Qh(scaled)/Kh   [4 blk/CU]
    k_gemm2<u16, 1, true, false, 64, 128><<<dim3(128, 8), 256, 0, stream>>>(cond, Wqk_t, nullptr, qh_ws, kh_ws, 8192, 1024);
    // v proj (transposed): A=Wv_t, B=x (f32, convert-on-stage) -> Vb       [2 blk/CU]
    k_gemm2<u16, 2, false, true, 64, 128><<<dim3(8, 64), 256, 0, stream>>>(Wv_t, x, nullptr, vb_ws, nullptr, 512, 8192);
    k_flash<<<dim3(64, 8, 2), 256, 0, stream>>>(qh_ws, kh_ws, vb_ws, at_ws);
    // out proj: A=at, B=Wu_t, +bias -> f32 out                             [2 blk/CU]
    k_gemm2<float, 0, false, false, 64, 128><<<dim3(128, 4), 256, 0, stream>>>(at_ws, Wu_t, bu, out, nullptr, 8192, 512);
}

// Round 10
// 244.555 us; speedup vs baseline: 1.0709x; 1.0709x over previous
//
#include <hip/hip_runtime.h>

#define B_SZ 2
#define T_SZ 4096

typedef unsigned short u16;
typedef __attribute__((ext_vector_type(8))) short short8;
typedef __attribute__((ext_vector_type(4))) float f32x4;
typedef __attribute__((ext_vector_type(4))) unsigned short u16x4;

#define CEXP 0.51006973f   // (8^-0.5) * log2(e), folded into Q projection

__device__ __forceinline__ u16 f2bf(float f) {            // round-to-nearest-even
    unsigned int u;
    __builtin_memcpy(&u, &f, 4);
    u = (u + 0x7fffu + ((u >> 16) & 1u)) >> 16;
    return (u16)u;
}
__device__ __forceinline__ unsigned int rbits(float f) {  // bits + half-up round offset
    unsigned int u;
    __builtin_memcpy(&u, &f, 4);
    return u + 0x8000u;
}
__device__ __forceinline__ f32x4 mfma16(short8 a, short8 b, f32x4 c) {
    return __builtin_amdgcn_mfma_f32_16x16x32_bf16(a, b, c, 0, 0, 0);
}

// ---------- f32 -> bf16 elementwise, 4 elems/thread ----------
__global__ void k_cvt(const float* __restrict__ src, u16* __restrict__ dst) {
    int i = (blockIdx.x * 256 + threadIdx.x) * 4;
    float4 v = *(const float4*)(src + i);
    u16x4 o = { f2bf(v.x), f2bf(v.y), f2bf(v.z), f2bf(v.w) };
    *(u16x4*)(dst + i) = o;
}

// ---------- f32 [K][N] -> bf16 [N][K] (convert + transpose, weights only) ----------
__global__ void k_cvt_t(const float* __restrict__ src, u16* __restrict__ dst, int K, int N) {
    int idx = blockIdx.x * 256 + threadIdx.x;
    int k = idx / N, n = idx - k * N;
    dst[(size_t)n * K + k] = f2bf(src[idx]);
}

// ---------- LDS-tiled bf16 GEMM: C[M,N] = A[M,512] x Bt[N,512]^T ----------
// TM x TN tile, 4 waves (TM/2 x TN/2 quadrant each), BK=32, K=512 (16 iters).
// LDS rows 72 u16; coalesced 16B/lane staging; reg prefetch pinned by sched_barrier.
// MODE 0: C[row*N+col] (+bias). MODE 1 (qk): col<512 -> Qh[b,h,t,64]*CEXP else Kh.
// MODE 2 (v): row=ch, col=tok -> Vb[b,h,kt,64d,64k] blocked.
template <typename OutT, int MODE, int TM, int TN>
__global__ __launch_bounds__(256) void k_gemm2(const u16* __restrict__ A, const u16* __restrict__ Bt,
                                               const float* __restrict__ bias, OutT* __restrict__ C,
                                               OutT* __restrict__ C2, int M, int N) {
    const int K = 512;
    constexpr int MI = TM / 32, NJ = TN / 32;      // 16x16 tiles per wave quadrant
    constexpr int NA = TM / 64, NB = TN / 64;      // staging short8s per thread
    int m0 = blockIdx.x * TM, n0 = blockIdx.y * TN;
    int tid = threadIdx.x;
    int wave = tid >> 6, lane = tid & 63, l16 = lane & 15, q = lane >> 4;
    int mo = (wave & 1) * (TM / 2), no = (wave >> 1) * (TN / 2);

    __shared__ __align__(16) u16 As[TM * 72];
    __shared__ __align__(16) u16 Bs[TN * 72];

    f32x4 acc[MI][NJ];
#pragma unroll
    for (int i = 0; i < MI; ++i)
#pragma unroll
        for (int j = 0; j < NJ; ++j) acc[i][j] = (f32x4){0.f, 0.f, 0.f, 0.f};

    const u16* ap[NA]; const u16* bp[NB];
    short8 ra[NA], rb[NB];
#pragma unroll
    for (int jj = 0; jj < NA; ++jj) {
        int id = tid + 256 * jj;
        ap[jj] = A + (size_t)(m0 + (id >> 2)) * K + (id & 3) * 8;
        ra[jj] = *(const short8*)(ap[jj]);
    }
#pragma unroll
    for (int jj = 0; jj < NB; ++jj) {
        int id = tid + 256 * jj;
        bp[jj] = Bt + (size_t)(n0 + (id >> 2)) * K + (id & 3) * 8;
        rb[jj] = *(const short8*)(bp[jj]);
    }

#pragma unroll 1
    for (int k0 = 0; k0 < K; k0 += 32) {
        __syncthreads();
#pragma unroll
        for (int jj = 0; jj < NA; ++jj) {
            int id = tid + 256 * jj;
            *(short8*)(&As[(id >> 2) * 72 + (id & 3) * 8]) = ra[jj];
        }
#pragma unroll
        for (int jj = 0; jj < NB; ++jj) {
            int id = tid + 256 * jj;
            *(short8*)(&Bs[(id >> 2) * 72 + (id & 3) * 8]) = rb[jj];
        }
        __syncthreads();

        int kadv = (k0 + 32 < K) ? 32 : 0;
#pragma unroll
        for (int jj = 0; jj < NA; ++jj) { ap[jj] += kadv; ra[jj] = *(const short8*)(ap[jj]); }
#pragma unroll
        for (int jj = 0; jj < NB; ++jj) { bp[jj] += kadv; rb[jj] = *(const short8*)(bp[jj]); }
        __builtin_amdgcn_sched_barrier(0);

        short8 af[MI], bf[NJ];
#pragma unroll
        for (int i = 0; i < MI; ++i) af[i] = *(const short8*)(&As[(mo + i * 16 + l16) * 72 + q * 8]);
#pragma unroll
        for (int j = 0; j < NJ; ++j) bf[j] = *(const short8*)(&Bs[(no + j * 16 + l16) * 72 + q * 8]);
#pragma unroll
        for (int i = 0; i < MI; ++i)
#pragma unroll
            for (int j = 0; j < NJ; ++j) acc[i][j] = mfma16(af[i], bf[j], acc[i][j]);
    }

    // epilogue: D row = q*4+r (m), col = l16 (n)
#pragma unroll
    for (int i = 0; i < MI; ++i)
#pragma unroll
        for (int j = 0; j < NJ; ++j)
#pragma unroll
            for (int r = 0; r < 4; ++r) {
                int row = m0 + mo + i * 16 + q * 4 + r;
                int col = n0 + no + j * 16 + l16;
                float val = acc[i][j][r];
                if constexpr (MODE == 0) {
                    val += bias ? bias[col] : 0.f;
                    if constexpr (__is_same(OutT, float)) C[(size_t)row * N + col] = val;
                    else                                  C[(size_t)row * N + col] = f2bf(val);
                } else if constexpr (MODE == 1) {
                    int b = row >> 12, t = row & 4095, h = (col & 511) >> 6, d = col & 63;
                    size_t addr = ((size_t)((b * 8 + h) * 4096 + t)) * 64 + d;
                    if (col < 512) C[addr] = f2bf(val * CEXP);
                    else           C2[addr] = f2bf(val);
                } else { // MODE 2
                    int h = row >> 6, d = row & 63, b = col >> 12, t = col & 4095;
                    int kt = t >> 6, k64 = t & 63;
                    size_t addr = ((((size_t)(b * 8 + h) * 64 + kt) * 64 + d) << 6) + k64;
                    C[addr] = f2bf(val);
                }
            }
}

// ---------- flash attention: LDS-tiled + register S^T trick + raw v_exp ----------
// grid (T/64, H, B); block 256 = 4 waves; wave owns 16 q rows. 64-key LDS tiles.
// Qh (pre-scaled by CEXP)/Kh: [b,h,t,64]; Vb: [b,h,kt,64d,64k] blocked.
// S^T trick: A=K rows pi0(l16)=(l16>>2)*8+(l16&3), pi0+4 -> lane (l16,q) holds
// P[qrow=l16][keys q*8..q*8+7] = PV B-frag. PV: A=V^T -> O^T in regs.
// exp via __builtin_amdgcn_exp2f (bare v_exp_f32 -- args bounded |x|<~25, no
// fixup code needed; library exp2f added ~8 range-check VALU ops per call).
// P packed via v_perm (round-half-up). l via ones-A MFMA (no shuffles).
__global__ __launch_bounds__(256) void k_flash(const u16* __restrict__ Qh, const u16* __restrict__ Kh,
                                               const u16* __restrict__ Vb, u16* __restrict__ o) {
    int qt = blockIdx.x, h = blockIdx.y, b = blockIdx.z;
    int tid = threadIdx.x;
    int wave = tid >> 6, lane = tid & 63, l16 = lane & 15, q = lane >> 4;

    __shared__ __align__(16) u16 Kt[64 * 80];   // [key][d], rows padded to 160B
    __shared__ __align__(16) u16 Vt[64 * 72];   // [d][key], rows padded to 144B

    int head = b * 8 + h;
    const u16* qp = Qh + ((size_t)head * 4096 + qt * 64 + wave * 16 + l16) * 64 + q * 8;
    short8 qf0 = *(const short8*)(qp);
    short8 qf1 = *(const short8*)(qp + 32);

    const u16* kc = Kh + (size_t)head * 4096 * 64;   // tile kt: advance 4096 u16 (8KB)
    const u16* vc = Vb + (size_t)head * 4096 * 64;

    int r0 = tid >> 3, g0 = tid & 7;                 // key/d row 0..31, 16B granule
    u16* kw0 = &Kt[r0 * 80 + g0 * 8];
    u16* kw1 = &Kt[(r0 + 32) * 80 + g0 * 8];
    u16* vw0 = &Vt[r0 * 72 + g0 * 8];
    u16* vw1 = &Vt[(r0 + 32) * 72 + g0 * 8];

    f32x4 oacc[4];
#pragma unroll
    for (int c = 0; c < 4; ++c) oacc[c] = (f32x4){0.f, 0.f, 0.f, 0.f};
    f32x4 lacc = (f32x4){0.f, 0.f, 0.f, 0.f};
    const short8 ones = { 0x3F80, 0x3F80, 0x3F80, 0x3F80, 0x3F80, 0x3F80, 0x3F80, 0x3F80 };
    int pi0 = (l16 >> 2) * 8 + (l16 & 3);

    short8 rk0 = *(const short8*)(kc + tid * 8);
    short8 rk1 = *(const short8*)(kc + tid * 8 + 2048);
    short8 rv0 = *(const short8*)(vc + tid * 8);
    short8 rv1 = *(const short8*)(vc + tid * 8 + 2048);

#pragma unroll 1
    for (int kt = 0; kt < 64; ++kt) {
        __syncthreads();
        *(short8*)kw0 = rk0;
        *(short8*)kw1 = rk1;
        *(short8*)vw0 = rv0;
        *(short8*)vw1 = rv1;
        __syncthreads();

        int adv = (kt < 63) ? 4096 : 0;              // last iter: harmless re-load
        kc += adv; vc += adv;
        rk0 = *(const short8*)(kc + tid * 8);
        rk1 = *(const short8*)(kc + tid * 8 + 2048);
        rv0 = *(const short8*)(vc + tid * 8);
        rv1 = *(const short8*)(vc + tid * 8 + 2048);
        __builtin_amdgcn_sched_barrier(0);

#pragma unroll
        for (int kk = 0; kk < 2; ++kk) {             // two 32-key subtiles
            const u16* ka = &Kt[(kk * 32 + pi0) * 80 + q * 8];
            short8 A00 = *(const short8*)(ka);
            short8 A01 = *(const short8*)(ka + 32);
            short8 A10 = *(const short8*)(ka + 4 * 80);
            short8 A11 = *(const short8*)(ka + 4 * 80 + 32);
            f32x4 s0 = (f32x4){0.f, 0.f, 0.f, 0.f};
            f32x4 s1 = (f32x4){0.f, 0.f, 0.f, 0.f};
            s0 = mfma16(A00, qf0, s0); s0 = mfma16(A01, qf1, s0);  // S^T keys q*8+r
            s1 = mfma16(A10, qf0, s1); s1 = mfma16(A11, qf1, s1);  // S^T keys q*8+4+r

            uint4 pd;
            pd.x = __builtin_amdgcn_perm(rbits(__builtin_amdgcn_exp2f(s0[1])),
                                         rbits(__builtin_amdgcn_exp2f(s0[0])), 0x07060302u);
            pd.y = __builtin_amdgcn_perm(rbits(__builtin_amdgcn_exp2f(s0[3])),
                                         rbits(__builtin_amdgcn_exp2f(s0[2])), 0x07060302u);
            pd.z = __builtin_amdgcn_perm(rbits(__builtin_amdgcn_exp2f(s1[1])),
                                         rbits(__builtin_amdgcn_exp2f(s1[0])), 0x07060302u);
            pd.w = __builtin_amdgcn_perm(rbits(__builtin_amdgcn_exp2f(s1[3])),
                                         rbits(__builtin_amdgcn_exp2f(s1[2])), 0x07060302u);
            short8 pf;
            __builtin_memcpy(&pf, &pd, 16);

            lacc = mfma16(ones, pf, lacc);           // l[qrow=l16] += slab sum
#pragma unroll
            for (int c = 0; c < 4; ++c) {
                short8 vfc = *(const short8*)(&Vt[(c * 16 + l16) * 72 + kk * 32 + q * 8]);
                oacc[c] = mfma16(vfc, pf, oacc[c]);  // O^T[d=c*16+q*4+r][qrow=l16]
            }
        }
    }

    float inv = 1.f / lacc[0];                       // every lane holds full l[qrow=l16]

    u16* ob = o + (size_t)(b * T_SZ + qt * 64 + wave * 16 + l16) * 512 + h * 64 + q * 4;
#pragma unroll
    for (int c = 0; c < 4; ++c) {
        u16x4 w = { f2bf(oacc[c][0] * inv), f2bf(oacc[c][1] * inv),
                    f2bf(oacc[c][2] * inv), f2bf(oacc[c][3] * inv) };
        *(u16x4*)(ob + c * 16) = w;
    }
}

extern "C" void kernel_launch(void* const* d_in, const int* in_sizes, int n_in,
                              void* d_out, int out_size, void* d_ws, size_t ws_size,
                              hipStream_t stream) {
    const float* x    = (const float*)d_in[0];   // [2,4096,512] f32
    const float* cond = (const float*)d_in[1];   // [2,4096,512] f32
    const float* Wqk  = (const float*)d_in[2];   // [512,1024]   f32
    const float* Wv   = (const float*)d_in[3];   // [512,512]    f32
    const float* Wu   = (const float*)d_in[4];   // [512,512]    f32
    const float* bu   = (const float*)d_in[5];   // [512]        f32
    float* out = (float*)d_out;                  // [2,4096,512] f32

    const size_t MT = (size_t)B_SZ * T_SZ;       // 8192
    u16* xb    = (u16*)d_ws;                     // [8192,512]          8 MB
    u16* cb    = xb + MT * 512;                  // [8192,512]          8 MB
    u16* qh_ws = cb + MT * 512;                  // [16 heads,4096,64]  8 MB (Q pre-scaled)
    u16* kh_ws = qh_ws + MT * 512;               // [16 heads,4096,64]  8 MB
    u16* vb_ws = kh_ws + MT * 512;               // [16,64kt,64d,64k]   8 MB
    u16* at_ws = vb_ws + MT * 512;               // [8192,512]          8 MB
    u16* Wqk_t = at_ws + MT * 512;               // [1024,512]          1 MB
    u16* Wv_t  = Wqk_t + (size_t)1024 * 512;     // [512,512]         0.5 MB
    u16* Wu_t  = Wv_t + (size_t)512 * 512;       // [512,512]         0.5 MB

    k_cvt<<<(int)(MT * 512 / 1024), 256, 0, stream>>>(x, xb);
    k_cvt<<<(int)(MT * 512 / 1024), 256, 0, stream>>>(cond, cb);
    k_cvt_t<<<(512 * 1024) / 256, 256, 0, stream>>>(Wqk, Wqk_t, 512, 1024);
    k_cvt_t<<<(512 * 512) / 256, 256, 0, stream>>>(Wv, Wv_t, 512, 512);
    k_cvt_t<<<(512 * 512) / 256, 256, 0, stream>>>(Wu, Wu_t, 512, 512);

    // qk proj: TN=256 -> A(cb,16MB) re-read only 4x; B=Wqk_t 2MB L2-resident. 512 blk = 2/CU.
    k_gemm2<u16, 1, 64, 256><<<dim3(128, 4), 256, 0, stream>>>(cb, Wqk_t, nullptr, qh_ws, kh_ws, 8192, 1024);
    // v proj (transposed): TM=128 -> B(xb,16MB) re-read only 4x. 512 blk = 2/CU.
    k_gemm2<u16, 2, 128, 64><<<dim3(4, 128), 256, 0, stream>>>(Wv_t, xb, nullptr, vb_ws, nullptr, 512, 8192);
    k_flash<<<dim3(64, 8, 2), 256, 0, stream>>>(qh_ws, kh_ws, vb_ws, at_ws);
    // out proj: A=at 8MB re-read 4x. 512 blk = 2/CU.
    k_gemm2<float, 0, 64, 128><<<dim3(128, 4), 256, 0, stream>>>(at_ws, Wu_t, bu, out, nullptr, 8192, 512);
}

// Round 11
// 238.501 us; speedup vs baseline: 1.0981x; 1.0254x over previous
//
#include <hip/hip_runtime.h>

#define B_SZ 2
#define T_SZ 4096

typedef unsigned short u16;
typedef __attribute__((ext_vector_type(8))) short short8;
typedef __attribute__((ext_vector_type(4))) float f32x4;
typedef __attribute__((ext_vector_type(4))) unsigned short u16x4;

#define CEXP 0.51006973f   // (8^-0.5) * log2(e), folded into Q projection

__device__ __forceinline__ u16 f2bf(float f) {            // round-to-nearest-even
    unsigned int u;
    __builtin_memcpy(&u, &f, 4);
    u = (u + 0x7fffu + ((u >> 16) & 1u)) >> 16;
    return (u16)u;
}
__device__ __forceinline__ unsigned int rbits(float f) {  // bits + half-up round offset
    unsigned int u;
    __builtin_memcpy(&u, &f, 4);
    return u + 0x8000u;
}
__device__ __forceinline__ f32x4 mfma16(short8 a, short8 b, f32x4 c) {
    return __builtin_amdgcn_mfma_f32_16x16x32_bf16(a, b, c, 0, 0, 0);
}

// ---------- fused prep: x->bf16, cond->bf16, 3 weight transposes (1 launch) ----------
__global__ void k_prep(const float* __restrict__ x, const float* __restrict__ cond,
                       const float* __restrict__ Wqk, const float* __restrict__ Wv,
                       const float* __restrict__ Wu, u16* __restrict__ xb, u16* __restrict__ cb,
                       u16* __restrict__ Wqk_t, u16* __restrict__ Wv_t, u16* __restrict__ Wu_t) {
    int blk = blockIdx.x;
    if (blk < 8192) {                                     // x / cond convert, 4 elems/thread
        const float* s = blk < 4096 ? x : cond;
        u16* d = blk < 4096 ? xb : cb;
        int i = ((blk & 4095) * 256 + threadIdx.x) * 4;
        float4 v = *(const float4*)(s + i);
        u16x4 o = { f2bf(v.x), f2bf(v.y), f2bf(v.z), f2bf(v.w) };
        *(u16x4*)(d + i) = o;
    } else if (blk < 10240) {                             // Wqk [512][1024] -> [1024][512]
        int idx = (blk - 8192) * 256 + threadIdx.x;
        Wqk_t[(size_t)(idx & 1023) * 512 + (idx >> 10)] = f2bf(Wqk[idx]);
    } else if (blk < 11264) {                             // Wv [512][512] -> T
        int idx = (blk - 10240) * 256 + threadIdx.x;
        Wv_t[(size_t)(idx & 511) * 512 + (idx >> 9)] = f2bf(Wv[idx]);
    } else {                                              // Wu [512][512] -> T
        int idx = (blk - 11264) * 256 + threadIdx.x;
        Wu_t[(size_t)(idx & 511) * 512 + (idx >> 9)] = f2bf(Wu[idx]);
    }
}

// ---------- LDS-tiled bf16 GEMM: D = A[M,512] x Bt[N,512]^T, orientation-tuned ----------
// TM x TN tile, 4 waves ((TM/2)x(TN/2) quadrant each), BK=32, K=512 (16 iters).
// D layout: lane (q,l16) reg r -> Mrow = q*4+r (consecutive!), Ncol = l16.
// MODE 1 (qk): A=Wqk_t (M=1024 ch), B=cond_b (N=8192 tok). regs = 4 consecutive d
//   -> u16x4 stores into Qh[b,h,t,64] (*CEXP) / Kh.
// MODE 2 (v):  A=Wv_t (M=512 ch),  B=xb (N=8192 tok) -> Vb[b,h,kt,d,64k] scalar u16.
// MODE 0 (out):A=Wu_t (M=512 cho), B=at (N=8192 tok). regs = 4 consecutive cho
//   -> float4 (+float4 bias) stores into out[t][512].
template <typename OutT, int MODE, int TM, int TN>
__global__ __launch_bounds__(256) void k_gemm3(const u16* __restrict__ A, const u16* __restrict__ Bt,
                                               const float* __restrict__ bias, OutT* __restrict__ C,
                                               OutT* __restrict__ C2) {
    const int K = 512;
    constexpr int MI = TM / 32, NJ = TN / 32;      // 16x16 tiles per wave quadrant
    constexpr int NA = TM / 64, NB = TN / 64;      // staging short8s per thread
    int m0 = blockIdx.x * TM, n0 = blockIdx.y * TN;
    int tid = threadIdx.x;
    int wave = tid >> 6, lane = tid & 63, l16 = lane & 15, q = lane >> 4;
    int mo = (wave & 1) * (TM / 2), no = (wave >> 1) * (TN / 2);

    __shared__ __align__(16) u16 As[TM * 72];
    __shared__ __align__(16) u16 Bs[TN * 72];

    f32x4 acc[MI][NJ];
#pragma unroll
    for (int i = 0; i < MI; ++i)
#pragma unroll
        for (int j = 0; j < NJ; ++j) acc[i][j] = (f32x4){0.f, 0.f, 0.f, 0.f};

    const u16* ap[NA]; const u16* bp[NB];
    short8 ra[NA], rb[NB];
#pragma unroll
    for (int jj = 0; jj < NA; ++jj) {
        int id = tid + 256 * jj;
        ap[jj] = A + (size_t)(m0 + (id >> 2)) * K + (id & 3) * 8;
        ra[jj] = *(const short8*)(ap[jj]);
    }
#pragma unroll
    for (int jj = 0; jj < NB; ++jj) {
        int id = tid + 256 * jj;
        bp[jj] = Bt + (size_t)(n0 + (id >> 2)) * K + (id & 3) * 8;
        rb[jj] = *(const short8*)(bp[jj]);
    }

#pragma unroll 1
    for (int k0 = 0; k0 < K; k0 += 32) {
        __syncthreads();
#pragma unroll
        for (int jj = 0; jj < NA; ++jj) {
            int id = tid + 256 * jj;
            *(short8*)(&As[(id >> 2) * 72 + (id & 3) * 8]) = ra[jj];
        }
#pragma unroll
        for (int jj = 0; jj < NB; ++jj) {
            int id = tid + 256 * jj;
            *(short8*)(&Bs[(id >> 2) * 72 + (id & 3) * 8]) = rb[jj];
        }
        __syncthreads();

        int kadv = (k0 + 32 < K) ? 32 : 0;
#pragma unroll
        for (int jj = 0; jj < NA; ++jj) { ap[jj] += kadv; ra[jj] = *(const short8*)(ap[jj]); }
#pragma unroll
        for (int jj = 0; jj < NB; ++jj) { bp[jj] += kadv; rb[jj] = *(const short8*)(bp[jj]); }
        __builtin_amdgcn_sched_barrier(0);

        short8 af[MI], bf[NJ];
#pragma unroll
        for (int i = 0; i < MI; ++i) af[i] = *(const short8*)(&As[(mo + i * 16 + l16) * 72 + q * 8]);
#pragma unroll
        for (int j = 0; j < NJ; ++j) bf[j] = *(const short8*)(&Bs[(no + j * 16 + l16) * 72 + q * 8]);
#pragma unroll
        for (int i = 0; i < MI; ++i)
#pragma unroll
            for (int j = 0; j < NJ; ++j) acc[i][j] = mfma16(af[i], bf[j], acc[i][j]);
    }

    // epilogue: Mrow = m0+mo+i*16+q*4+r (r consecutive), Ncol = n0+no+j*16+l16
#pragma unroll
    for (int i = 0; i < MI; ++i) {
        int chb = m0 + mo + i * 16 + q * 4;                    // 4-aligned channel base
#pragma unroll
        for (int j = 0; j < NJ; ++j) {
            int trow = n0 + no + j * 16 + l16;                 // global token row (b*4096+t)
            if constexpr (MODE == 0) {                         // out proj: float4 + bias
                float4 bb = *(const float4*)(bias + chb);
                float4 w = { acc[i][j][0] + bb.x, acc[i][j][1] + bb.y,
                             acc[i][j][2] + bb.z, acc[i][j][3] + bb.w };
                *(float4*)(&C[(size_t)trow * 512 + chb]) = w;
            } else if constexpr (MODE == 1) {                  // qk proj: u16x4 into Qh/Kh
                int b = trow >> 12, t = trow & 4095;
                int h = (chb & 511) >> 6, d = chb & 63;
                size_t addr = ((size_t)((b * 8 + h) * 4096 + t)) * 64 + d;
                if (chb < 512) {
                    u16x4 w = { f2bf(acc[i][j][0] * CEXP), f2bf(acc[i][j][1] * CEXP),
                                f2bf(acc[i][j][2] * CEXP), f2bf(acc[i][j][3] * CEXP) };
                    *(u16x4*)(&C[addr]) = w;
                } else {
                    u16x4 w = { f2bf(acc[i][j][0]), f2bf(acc[i][j][1]),
                                f2bf(acc[i][j][2]), f2bf(acc[i][j][3]) };
                    *(u16x4*)(&C2[addr]) = w;
                }
            } else {                                           // v proj: Vb blocked, scalar
                int b = trow >> 12, t = trow & 4095;
                int kt = t >> 6, k64 = t & 63;
                int h = chb >> 6;
#pragma unroll
                for (int r = 0; r < 4; ++r) {
                    int d = (chb + r) & 63;
                    size_t addr = ((((size_t)(b * 8 + h) * 64 + kt) * 64 + d) << 6) + k64;
                    C[addr] = f2bf(acc[i][j][r]);
                }
            }
        }
    }
}

// ---------- flash attention (unchanged from round 10: validated 116 us) ----------
__global__ __launch_bounds__(256) void k_flash(const u16* __restrict__ Qh, const u16* __restrict__ Kh,
                                               const u16* __restrict__ Vb, u16* __restrict__ o) {
    int qt = blockIdx.x, h = blockIdx.y, b = blockIdx.z;
    int tid = threadIdx.x;
    int wave = tid >> 6, lane = tid & 63, l16 = lane & 15, q = lane >> 4;

    __shared__ __align__(16) u16 Kt[64 * 80];   // [key][d], rows padded to 160B
    __shared__ __align__(16) u16 Vt[64 * 72];   // [d][key], rows padded to 144B

    int head = b * 8 + h;
    const u16* qp = Qh + ((size_t)head * 4096 + qt * 64 + wave * 16 + l16) * 64 + q * 8;
    short8 qf0 = *(const short8*)(qp);
    short8 qf1 = *(const short8*)(qp + 32);

    const u16* kc = Kh + (size_t)head * 4096 * 64;
    const u16* vc = Vb + (size_t)head * 4096 * 64;

    int r0 = tid >> 3, g0 = tid & 7;
    u16* kw0 = &Kt[r0 * 80 + g0 * 8];
    u16* kw1 = &Kt[(r0 + 32) * 80 + g0 * 8];
    u16* vw0 = &Vt[r0 * 72 + g0 * 8];
    u16* vw1 = &Vt[(r0 + 32) * 72 + g0 * 8];

    f32x4 oacc[4];
#pragma unroll
    for (int c = 0; c < 4; ++c) oacc[c] = (f32x4){0.f, 0.f, 0.f, 0.f};
    f32x4 lacc = (f32x4){0.f, 0.f, 0.f, 0.f};
    const short8 ones = { 0x3F80, 0x3F80, 0x3F80, 0x3F80, 0x3F80, 0x3F80, 0x3F80, 0x3F80 };
    int pi0 = (l16 >> 2) * 8 + (l16 & 3);

    short8 rk0 = *(const short8*)(kc + tid * 8);
    short8 rk1 = *(const short8*)(kc + tid * 8 + 2048);
    short8 rv0 = *(const short8*)(vc + tid * 8);
    short8 rv1 = *(const short8*)(vc + tid * 8 + 2048);

#pragma unroll 1
    for (int kt = 0; kt < 64; ++kt) {
        __syncthreads();
        *(short8*)kw0 = rk0;
        *(short8*)kw1 = rk1;
        *(short8*)vw0 = rv0;
        *(short8*)vw1 = rv1;
        __syncthreads();

        int adv = (kt < 63) ? 4096 : 0;
        kc += adv; vc += adv;
        rk0 = *(const short8*)(kc + tid * 8);
        rk1 = *(const short8*)(kc + tid * 8 + 2048);
        rv0 = *(const short8*)(vc + tid * 8);
        rv1 = *(const short8*)(vc + tid * 8 + 2048);
        __builtin_amdgcn_sched_barrier(0);

#pragma unroll
        for (int kk = 0; kk < 2; ++kk) {
            const u16* ka = &Kt[(kk * 32 + pi0) * 80 + q * 8];
            short8 A00 = *(const short8*)(ka);
            short8 A01 = *(const short8*)(ka + 32);
            short8 A10 = *(const short8*)(ka + 4 * 80);
            short8 A11 = *(const short8*)(ka + 4 * 80 + 32);
            f32x4 s0 = (f32x4){0.f, 0.f, 0.f, 0.f};
            f32x4 s1 = (f32x4){0.f, 0.f, 0.f, 0.f};
            s0 = mfma16(A00, qf0, s0); s0 = mfma16(A01, qf1, s0);
            s1 = mfma16(A10, qf0, s1); s1 = mfma16(A11, qf1, s1);

            uint4 pd;
            pd.x = __builtin_amdgcn_perm(rbits(__builtin_amdgcn_exp2f(s0[1])),
                                         rbits(__builtin_amdgcn_exp2f(s0[0])), 0x07060302u);
            pd.y = __builtin_amdgcn_perm(rbits(__builtin_amdgcn_exp2f(s0[3])),
                                         rbits(__builtin_amdgcn_exp2f(s0[2])), 0x07060302u);
            pd.z = __builtin_amdgcn_perm(rbits(__builtin_amdgcn_exp2f(s1[1])),
                                         rbits(__builtin_amdgcn_exp2f(s1[0])), 0x07060302u);
            pd.w = __builtin_amdgcn_perm(rbits(__builtin_amdgcn_exp2f(s1[3])),
                                         rbits(__builtin_amdgcn_exp2f(s1[2])), 0x07060302u);
            short8 pf;
            __builtin_memcpy(&pf, &pd, 16);

            lacc = mfma16(ones, pf, lacc);
#pragma unroll
            for (int c = 0; c < 4; ++c) {
                short8 vfc = *(const short8*)(&Vt[(c * 16 + l16) * 72 + kk * 32 + q * 8]);
                oacc[c] = mfma16(vfc, pf, oacc[c]);
            }
        }
    }

    float inv = 1.f / lacc[0];

    u16* ob = o + (size_t)(b * T_SZ + qt * 64 + wave * 16 + l16) * 512 + h * 64 + q * 4;
#pragma unroll
    for (int c = 0; c < 4; ++c) {
        u16x4 w = { f2bf(oacc[c][0] * inv), f2bf(oacc[c][1] * inv),
                    f2bf(oacc[c][2] * inv), f2bf(oacc[c][3] * inv) };
        *(u16x4*)(ob + c * 16) = w;
    }
}

extern "C" void kernel_launch(void* const* d_in, const int* in_sizes, int n_in,
                              void* d_out, int out_size, void* d_ws, size_t ws_size,
                              hipStream_t stream) {
    const float* x    = (const float*)d_in[0];   // [2,4096,512] f32
    const float* cond = (const float*)d_in[1];   // [2,4096,512] f32
    const float* Wqk  = (const float*)d_in[2];   // [512,1024]   f32
    const float* Wv   = (const float*)d_in[3];   // [512,512]    f32
    const float* Wu   = (const float*)d_in[4];   // [512,512]    f32
    const float* bu   = (const float*)d_in[5];   // [512]        f32
    float* out = (float*)d_out;                  // [2,4096,512] f32

    const size_t MT = (size_t)B_SZ * T_SZ;       // 8192
    u16* xb    = (u16*)d_ws;                     // [8192,512]          8 MB
    u16* cb    = xb + MT * 512;                  // [8192,512]          8 MB
    u16* qh_ws = cb + MT * 512;                  // [16 heads,4096,64]  8 MB (Q pre-scaled)
    u16* kh_ws = qh_ws + MT * 512;               // [16 heads,4096,64]  8 MB
    u16* vb_ws = kh_ws + MT * 512;               // [16,64kt,64d,64k]   8 MB
    u16* at_ws = vb_ws + MT * 512;               // [8192,512]          8 MB
    u16* Wqk_t = at_ws + MT * 512;               // [1024,512]          1 MB
    u16* Wv_t  = Wqk_t + (size_t)1024 * 512;     // [512,512]         0.5 MB
    u16* Wu_t  = Wv_t + (size_t)512 * 512;       // [512,512]         0.5 MB

    k_prep<<<12288, 256, 0, stream>>>(x, cond, Wqk, Wv, Wu, xb, cb, Wqk_t, Wv_t, Wu_t);

    // qk proj: A=Wqk_t (1024 ch), B=cb (8192 tok). grid (1024/256, 8192/64) = 512 blocks.
    k_gemm3<u16, 1, 256, 64><<<dim3(4, 128), 256, 0, stream>>>(Wqk_t, cb, nullptr, qh_ws, kh_ws);
    // v proj: A=Wv_t (512 ch), B=xb. grid (512/128, 128) = 512 blocks.
    k_gemm3<u16, 2, 128, 64><<<dim3(4, 128), 256, 0, stream>>>(Wv_t, xb, nullptr, vb_ws, nullptr);
    k_flash<<<dim3(64, 8, 2), 256, 0, stream>>>(qh_ws, kh_ws, vb_ws, at_ws);
    // out proj: A=Wu_t (512 cho), B=at, +bias, float4 stores. grid (4, 128) = 512 blocks.
    k_gemm3<float, 0, 128, 64><<<dim3(4, 128), 256, 0, stream>>>(Wu_t, at_ws, bu, out, nullptr);
}